// Round 10
// baseline (271.848 us; speedup 1.0000x reference)
//
#include <hip/hip_runtime.h>

// ---------------- constants ----------------
#define BATCH   131072
#define INDIM   1024
#define BM      64
#define BDIM    512
#define NBLK    (BATCH / BM)          // 2048

// ---- LDS layout (bytes): only activations live in LDS now ----
#define Z1_OFF   0                    // z1 [64][392] bf16 (50176)
#define FZ_OFF   0                    // fused [64][264] bf16 (33792), aliases z1 later
#define RP_OFF   33792                // rowpart [64][8] f32 (2048), after fz
#define XTA_OFF  50176                // x-tile pair A: 2x[64][32] bf16 (8192) -> 58368
#define XTB_OFF  58368                // pair B -> 66560
#define CB_OFF   66560
#define B1S_OFF  (CB_OFF)             // 384 f32
#define B2S_OFF  (CB_OFF + 1536)      // 128 f32
#define B3S_OFF  (CB_OFF + 2048)      // 384 f32
#define W4S_OFF  (CB_OFF + 3584)      // 384 f32
#define MKS_OFF  (CB_OFF + 5120)      // mk bf16 [32][136] (8704)
#define SMEM_BYTES (CB_OFF + 13824)   // 80384 -> 2 blocks/CU

typedef unsigned short u16;
typedef u16    u16x8  __attribute__((ext_vector_type(8)));
typedef u16    u16x4  __attribute__((ext_vector_type(4)));
typedef __bf16 bf16x8 __attribute__((ext_vector_type(8)));
typedef __bf16 bf16x4 __attribute__((ext_vector_type(4)));
typedef float  f32x4  __attribute__((ext_vector_type(4)));

__device__ __forceinline__ u16 f2bf(float f) {
  unsigned u = __float_as_uint(f);
  u += 0x7FFFu + ((u >> 16) & 1u);    // RNE
  return (u16)(u >> 16);
}

// tanh-form GELU via sigmoid (max abs err ~3e-4, budget 1e-2)
__device__ __forceinline__ float gelu_fast(float v) {
  float t = v * v;
  float u = v * fmaf(t, 0.0356774081f, 0.7978845608f);
  float e = __builtin_amdgcn_exp2f(u * -2.885390082f);
  return v * __builtin_amdgcn_rcpf(1.0f + e);
}

__device__ __forceinline__ f32x4 mfma16(u16x8 a, u16x8 b, f32x4 c) {
  return __builtin_amdgcn_mfma_f32_16x16x32_bf16(
      __builtin_bit_cast(bf16x8, a), __builtin_bit_cast(bf16x8, b), c, 0, 0, 0);
}

__device__ __forceinline__ u16x8 cvt8(float4 a, float4 b) {
  bf16x8 r;
  r[0]=(__bf16)a.x; r[1]=(__bf16)a.y; r[2]=(__bf16)a.z; r[3]=(__bf16)a.w;
  r[4]=(__bf16)b.x; r[5]=(__bf16)b.y; r[6]=(__bf16)b.z; r[7]=(__bf16)b.w;
  return __builtin_bit_cast(u16x8, r);
}
__device__ __forceinline__ u16x4 cvt4(float4 a) {
  bf16x4 r;
  r[0]=(__bf16)a.x; r[1]=(__bf16)a.y; r[2]=(__bf16)a.z; r[3]=(__bf16)a.w;
  return __builtin_bit_cast(u16x4, r);
}

// lgkm-only barrier: register W-loads (vmcnt) stay in flight across phases;
// compiler inserts its own vmcnt before each use of a loaded register.
#define BARRIER_LGKM do { \
  asm volatile("s_waitcnt lgkmcnt(0)" ::: "memory"); \
  __builtin_amdgcn_s_barrier(); \
  __builtin_amdgcn_sched_barrier(0); } while (0)

// ------- prep: bf16-cast + transpose into FRAGMENT-MAJOR layout -------
// w1f: [kt=32][wid=8][n=3][lane=64][8]  (col = wid*48+n*16+(lane&15), k = kt*32+(lane>>4)*8+o)
// w2f: [kt=12][wid=8][lane=64][8]       (col = wid*16+(lane&15))
// w3f: [kt= 8][wid=8][n=3][lane=64][8]  (col = wid*48+n*16+(lane&15))
__global__ void prep_kernel(const float* __restrict__ w1, const float* __restrict__ w2,
                            const float* __restrict__ w3, u16* __restrict__ w1f,
                            u16* __restrict__ w2f, u16* __restrict__ w3f) {
  int i = blockIdx.x * 256 + threadIdx.x;
  if (i < 393216) {
    int o = i & 7, lane = (i >> 3) & 63;
    int rest = i >> 9;                 // (kt*8+wid)*3+n
    int n = rest % 3, rw = rest / 3;
    int wid = rw & 7, kt = rw >> 3;
    int col = wid * 48 + n * 16 + (lane & 15);
    int k = kt * 32 + (lane >> 4) * 8 + o;
    w1f[i] = f2bf(w1[k * 384 + col]);
  } else if (i < 442368) {
    int j = i - 393216;
    int o = j & 7, lane = (j >> 3) & 63;
    int rest = j >> 9;                 // kt*8+wid
    int wid = rest & 7, kt = rest >> 3;
    int col = wid * 16 + (lane & 15);
    int k = kt * 32 + (lane >> 4) * 8 + o;
    w2f[j] = f2bf(w2[k * 128 + col]);
  } else if (i < 540672) {
    int j = i - 442368;
    int o = j & 7, lane = (j >> 3) & 63;
    int rest = j >> 9;
    int n = rest % 3, rw = rest / 3;
    int wid = rw & 7, kt = rw >> 3;
    int col = wid * 48 + n * 16 + (lane & 15);
    int k = kt * 32 + (lane >> 4) * 8 + o;
    w3f[j] = f2bf(w3[k * 384 + col]);
  }
}

// ---------------- fused forward: 8 waves, wave tile 64x48, W in registers ----------------
__global__ __launch_bounds__(BDIM, 2) void fused_kernel(
    const float* __restrict__ x,  const u16* __restrict__ w1f,
    const float* __restrict__ b1, const u16* __restrict__ w2f,
    const float* __restrict__ b2, const float* __restrict__ mkw,
    const float* __restrict__ mvw, const u16* __restrict__ w3f,
    const float* __restrict__ b3, const float* __restrict__ w4,
    const float* __restrict__ b4, float* __restrict__ out) {
  extern __shared__ char smem[];
  u16*   z1  = (u16*)(smem + Z1_OFF);
  u16*   fz  = (u16*)(smem + FZ_OFF);
  float* b1s = (float*)(smem + B1S_OFF);
  float* b2s = (float*)(smem + B2S_OFF);
  float* b3s = (float*)(smem + B3S_OFF);
  float* w4s = (float*)(smem + W4S_OFF);
  u16*   mks = (u16*)(smem + MKS_OFF);
  float* rowpart = (float*)(smem + RP_OFF);

  const int tid  = threadIdx.x;
  const int lane = tid & 63;
  const int wid  = tid >> 6;          // 0..7: 48 w-cols (G1/G3), 16 (G2)
  const int l15  = lane & 15;
  const int g    = lane >> 4;         // 0..3
  const int sw8  = (g ^ ((l15 >> 1) & 3)) * 8;   // swizzled chunk (u16 offset)
  const int row0 = blockIdx.x * BM;
  const int wrow = wid * 48;

  // ---------- prologue ----------
  // W frag base (register path), issue kt0/kt1 frags first
  const u16* wp1 = w1f + wid * 1536 + lane * 8;     // + kt*12288 + n*512
  u16x8 wf0[3], wf1[3];
  #pragma unroll
  for (int n = 0; n < 3; ++n) wf0[n] = *(const u16x8*)(wp1 + n * 512);
  #pragma unroll
  for (int n = 0; n < 3; ++n) wf1[n] = *(const u16x8*)(wp1 + 12288 + n * 512);

  // x stream: thread covers row=tid>>3, quad xq=tid&7 (4 f32 per tile)
  const int xrow = tid >> 3, xq = tid & 7;
  const float* xp = x + (long)(row0 + xrow) * INDIM + xq * 4;
  const int xpub = xrow * 32 + (((xq >> 1) ^ ((xrow >> 1) & 3)) << 3) + (xq & 1) * 4;
  float4 xA = *(const float4*)xp;            // x(0)
  float4 xB = *(const float4*)(xp + 32);     // x(1)

  if (tid < 384) b1s[tid] = b1[tid];
  if (tid < 128) b2s[tid] = b2[tid];
  if (tid < 384) b3s[tid] = b3[tid];
  if (tid < 384) w4s[tid] = w4[tid];
  {
    int r = tid >> 4, cc = (tid & 15) * 8;
    const float4* pm = (const float4*)(mkw + r * 128 + cc);
    *(u16x8*)(mks + r * 136 + cc) = cvt8(pm[0], pm[1]);
  }
  // publish xt0, xt1 into pair A
  *(u16x4*)((u16*)(smem + XTA_OFF) + xpub)        = cvt4(xA);
  *(u16x4*)((u16*)(smem + XTA_OFF) + 2048 + xpub) = cvt4(xB);
  // stream x(2), x(3)
  xA = *(const float4*)(xp + 64); xB = *(const float4*)(xp + 96);
  BARRIER_LGKM;

  // =========== GEMM1: z1 = gelu(x@w1+b1) [64x384], K=1024, 2 kt/phase ===========
  f32x4 acc[4][3];
  #pragma unroll
  for (int m = 0; m < 4; ++m)
    #pragma unroll
    for (int n = 0; n < 3; ++n) acc[m][n] = (f32x4){0.f, 0.f, 0.f, 0.f};

  for (int p = 0; p < 15; ++p) {
    const u16* xrb = (const u16*)(smem + ((p & 1) ? XTB_OFF : XTA_OFF));
    u16* xwb = (u16*)(smem + ((p & 1) ? XTA_OFF : XTB_OFF));
    // A frags for kt=2p, 2p+1 (LDS)
    u16x8 af0[4], af1[4];
    #pragma unroll
    for (int m = 0; m < 4; ++m) af0[m] = *(const u16x8*)(xrb + (m * 16 + l15) * 32 + sw8);
    #pragma unroll
    for (int m = 0; m < 4; ++m) af1[m] = *(const u16x8*)(xrb + 2048 + (m * 16 + l15) * 32 + sw8);
    // W frags for kt=2p+2, 2p+3 (register loads; full phase of flight)
    u16x8 wn0[3], wn1[3];
    #pragma unroll
    for (int n = 0; n < 3; ++n) wn0[n] = *(const u16x8*)(wp1 + (2 * p + 2) * 12288 + n * 512);
    #pragma unroll
    for (int n = 0; n < 3; ++n) wn1[n] = *(const u16x8*)(wp1 + (2 * p + 3) * 12288 + n * 512);
    // MFMA kt=2p
    #pragma unroll
    for (int m = 0; m < 4; ++m)
      #pragma unroll
      for (int n = 0; n < 3; ++n) acc[m][n] = mfma16(wf0[n], af0[m], acc[m][n]);
    // publish xt(2p+2), xt(2p+3); implicit vmcnt retires only older x-loads
    *(u16x4*)(xwb + xpub)        = cvt4(xA);
    *(u16x4*)(xwb + 2048 + xpub) = cvt4(xB);
    if (p < 14) {
      xA = *(const float4*)(xp + (2 * p + 4) * 32);
      xB = *(const float4*)(xp + (2 * p + 5) * 32);
    }
    // MFMA kt=2p+1
    #pragma unroll
    for (int m = 0; m < 4; ++m)
      #pragma unroll
      for (int n = 0; n < 3; ++n) acc[m][n] = mfma16(wf1[n], af1[m], acc[m][n]);
    #pragma unroll
    for (int n = 0; n < 3; ++n) { wf0[n] = wn0[n]; wf1[n] = wn1[n]; }
    BARRIER_LGKM;
  }
  {   // drain: kt 30,31 from pair B
    const u16* xrb = (const u16*)(smem + XTB_OFF);
    u16x8 af0[4], af1[4];
    #pragma unroll
    for (int m = 0; m < 4; ++m) af0[m] = *(const u16x8*)(xrb + (m * 16 + l15) * 32 + sw8);
    #pragma unroll
    for (int m = 0; m < 4; ++m) af1[m] = *(const u16x8*)(xrb + 2048 + (m * 16 + l15) * 32 + sw8);
    #pragma unroll
    for (int m = 0; m < 4; ++m)
      #pragma unroll
      for (int n = 0; n < 3; ++n) acc[m][n] = mfma16(wf0[n], af0[m], acc[m][n]);
    #pragma unroll
    for (int m = 0; m < 4; ++m)
      #pragma unroll
      for (int n = 0; n < 3; ++n) acc[m][n] = mfma16(wf1[n], af1[m], acc[m][n]);
  }
  // z1 epilogue: b64 writes of 4 consecutive cols (z1 region disjoint from XT)
  #pragma unroll
  for (int m = 0; m < 4; ++m) {
    #pragma unroll
    for (int n = 0; n < 3; ++n) {
      int col = wrow + n * 16 + g * 4;
      float4 bv = *(const float4*)(b1s + col);
      f32x4 a = acc[m][n];
      float4 gv = {gelu_fast(a[0] + bv.x), gelu_fast(a[1] + bv.y),
                   gelu_fast(a[2] + bv.z), gelu_fast(a[3] + bv.w)};
      *(u16x4*)(z1 + (m * 16 + l15) * 392 + col) = cvt4(gv);
    }
  }
  BARRIER_LGKM;                      // z1 visible

  // =========== GEMM2: z = gelu(z1@w2+b2) [64x128], K=384, reg-W, no barriers ===========
  const u16* wp2 = w2f + wid * 512 + lane * 8;      // + kt*4096
  f32x4 acc2[4];
  #pragma unroll
  for (int m = 0; m < 4; ++m) acc2[m] = (f32x4){0.f, 0.f, 0.f, 0.f};
  u16x8 w2c = *(const u16x8*)wp2;
  for (int kt = 0; kt < 12; ++kt) {
    u16x8 a2f[4];
    #pragma unroll
    for (int m = 0; m < 4; ++m)
      a2f[m] = *(const u16x8*)(z1 + (m * 16 + l15) * 392 + kt * 32 + g * 8);
    u16x8 w2n = (kt < 11) ? *(const u16x8*)(wp2 + (kt + 1) * 4096) : w2c;
    #pragma unroll
    for (int m = 0; m < 4; ++m) acc2[m] = mfma16(w2c, a2f[m], acc2[m]);
    w2c = w2n;
  }
  BARRIER_LGKM;                      // all z1 reads done -> fz may overwrite

  // fz epilogue (z part, cols wid*16..)
  #pragma unroll
  for (int m = 0; m < 4; ++m) {
    int col = wid * 16 + g * 4;
    float4 bv = *(const float4*)(b2s + col);
    f32x4 a = acc2[m];
    float4 gv = {gelu_fast(a[0] + bv.x), gelu_fast(a[1] + bv.y),
                 gelu_fast(a[2] + bv.z), gelu_fast(a[3] + bv.w)};
    *(u16x4*)(fz + (m * 16 + l15) * 264 + col) = cvt4(gv);
  }
  BARRIER_LGKM;                      // fz(z) visible

  // =========== logits + in-register top-2 + mem blend (waves 0..3, rows wid*16+l15) ===========
  if (wid < 4) {
    const int wr = wid * 16 + l15;
    f32x4 accl[2] = {(f32x4){0,0,0,0}, (f32x4){0,0,0,0}};
    #pragma unroll
    for (int ks = 0; ks < 4; ++ks) {
      u16x8 afz = *(const u16x8*)(fz + wr * 264 + ks * 32 + g * 8);
      u16x8 k0  = *(const u16x8*)(mks + l15 * 136 + ks * 32 + g * 8);
      u16x8 k1  = *(const u16x8*)(mks + (16 + l15) * 136 + ks * 32 + g * 8);
      accl[0] = mfma16(k0, afz, accl[0]);
      accl[1] = mfma16(k1, afz, accl[1]);
    }
    float m1 = -3.4e38f, m2 = -3.4e38f; int i1 = -1, i2 = -1;
    #pragma unroll
    for (int n = 0; n < 2; ++n)
      #pragma unroll
      for (int j = 0; j < 4; ++j) {
        float v = accl[n][j]; int idx = n * 16 + g * 4 + j;
        if (v > m1) { m2 = m1; i2 = i1; m1 = v; i1 = idx; }
        else if (v > m2) { m2 = v; i2 = idx; }
      }
    #pragma unroll
    for (int d = 16; d <= 32; d <<= 1) {   // merge across g-groups (same row)
      float om1 = __shfl_xor(m1, d); int oi1 = __shfl_xor(i1, d);
      float om2 = __shfl_xor(m2, d); int oi2 = __shfl_xor(i2, d);
      bool take = (om1 > m1) || (om1 == m1 && oi1 < i1);
      if (take) {
        float nm2; int ni2;
        if (m1 > om2 || (m1 == om2 && i1 < oi2)) { nm2 = m1; ni2 = i1; }
        else { nm2 = om2; ni2 = oi2; }
        m1 = om1; i1 = oi1; m2 = nm2; i2 = ni2;
      } else {
        if (om1 > m2 || (om1 == m2 && oi1 < i2)) { m2 = om1; i2 = oi1; }
      }
    }
    float a1 = __builtin_amdgcn_rcpf(
        1.0f + __builtin_amdgcn_exp2f((m2 - m1) * (1.44269504f / 0.7f)));
    float a2 = 1.0f - a1;
    const float* v1 = mvw + i1 * 128 + g * 32;
    const float* v2 = mvw + i2 * 128 + g * 32;
    #pragma unroll
    for (int c = 0; c < 4; ++c) {
      float4 A0 = *(const float4*)(v1 + c * 8), A1 = *(const float4*)(v1 + c * 8 + 4);
      float4 B0 = *(const float4*)(v2 + c * 8), B1 = *(const float4*)(v2 + c * 8 + 4);
      float4 r0 = {a1*A0.x + a2*B0.x, a1*A0.y + a2*B0.y, a1*A0.z + a2*B0.z, a1*A0.w + a2*B0.w};
      float4 r1 = {a1*A1.x + a2*B1.x, a1*A1.y + a2*B1.y, a1*A1.z + a2*B1.z, a1*A1.w + a2*B1.w};
      *(u16x8*)(fz + wr * 264 + 128 + g * 32 + c * 8) = cvt8(r0, r1);
    }
  }
  BARRIER_LGKM;                      // mem visible

  // =========== GEMM3: h = gelu(fused@w3+b3) [64x384], K=256, reg-W, no barriers ===========
  const u16* wp3 = w3f + wid * 1536 + lane * 8;     // + kt*12288 + n*512
  f32x4 acc3[4][3];
  #pragma unroll
  for (int m = 0; m < 4; ++m)
    #pragma unroll
    for (int n = 0; n < 3; ++n) acc3[m][n] = (f32x4){0.f, 0.f, 0.f, 0.f};
  u16x8 w3c[3];
  #pragma unroll
  for (int n = 0; n < 3; ++n) w3c[n] = *(const u16x8*)(wp3 + n * 512);
  for (int kt = 0; kt < 8; ++kt) {
    u16x8 a3f[4], w3n[3];
    #pragma unroll
    for (int m = 0; m < 4; ++m)
      a3f[m] = *(const u16x8*)(fz + (m * 16 + l15) * 264 + kt * 32 + g * 8);
    #pragma unroll
    for (int n = 0; n < 3; ++n)
      w3n[n] = (kt < 7) ? *(const u16x8*)(wp3 + (kt + 1) * 12288 + n * 512) : w3c[n];
    #pragma unroll
    for (int m = 0; m < 4; ++m)
      #pragma unroll
      for (int n = 0; n < 3; ++n) acc3[m][n] = mfma16(w3c[n], a3f[m], acc3[m][n]);
    #pragma unroll
    for (int n = 0; n < 3; ++n) w3c[n] = w3n[n];
  }

  // epilogue: per-row dot with w4; lane holds 4 consecutive cols -> 2-step shuffle reduce
  // (rowpart region [33792,35840) is disjoint from fz [0,33792) -> no barrier needed)
  #pragma unroll
  for (int m = 0; m < 4; ++m) {
    float s = 0.f;
    #pragma unroll
    for (int n = 0; n < 3; ++n) {
      int col = wrow + n * 16 + g * 4;
      float4 bv = *(const float4*)(b3s + col);
      float4 wv = *(const float4*)(w4s + col);
      f32x4 a = acc3[m][n];
      s += gelu_fast(a[0] + bv.x) * wv.x + gelu_fast(a[1] + bv.y) * wv.y +
           gelu_fast(a[2] + bv.z) * wv.z + gelu_fast(a[3] + bv.w) * wv.w;
    }
    s += __shfl_xor(s, 16);
    s += __shfl_xor(s, 32);
    if (lane < 16) rowpart[(m * 16 + l15) * 8 + wid] = s;
  }
  BARRIER_LGKM;
  if (tid < BM) {
    const float4* rp = (const float4*)(rowpart + tid * 8);
    float4 p0 = rp[0], p1 = rp[1];
    float lg = b4[0] + p0.x + p0.y + p0.z + p0.w + p1.x + p1.y + p1.z + p1.w;
    out[row0 + tid] = __builtin_amdgcn_rcpf(1.0f + __builtin_amdgcn_exp2f(-lg * 1.44269504f));
  }
}

// ---------------- launch ----------------
extern "C" void kernel_launch(void* const* d_in, const int* in_sizes, int n_in,
                              void* d_out, int out_size, void* d_ws, size_t ws_size,
                              hipStream_t stream) {
  const float* x  = (const float*)d_in[0];
  const float* w1 = (const float*)d_in[1];
  const float* b1 = (const float*)d_in[2];
  const float* w2 = (const float*)d_in[3];
  const float* b2 = (const float*)d_in[4];
  const float* mk = (const float*)d_in[5];
  const float* mv = (const float*)d_in[6];
  const float* w3 = (const float*)d_in[7];
  const float* b3 = (const float*)d_in[8];
  const float* w4 = (const float*)d_in[9];
  const float* b4 = (const float*)d_in[10];

  u16* w1f = (u16*)d_ws;            // 393216 u16, fragment-major
  u16* w2f = w1f + 393216;          // 49152
  u16* w3f = w1f + 442368;          // 98304

  prep_kernel<<<2112, 256, 0, stream>>>(w1, w2, w3, w1f, w2f, w3f);

  (void)hipFuncSetAttribute(reinterpret_cast<const void*>(fused_kernel),
                            hipFuncAttributeMaxDynamicSharedMemorySize, SMEM_BYTES);
  fused_kernel<<<NBLK, BDIM, SMEM_BYTES, stream>>>(x, w1f, b1, w2f, b2, mk, mv, w3f,
                                                   b3, w4, b4, (float*)d_out);
}